// Round 10
// baseline (108.575 us; speedup 1.0000x reference)
//
#include <hip/hip_runtime.h>
#include <hip/hip_bf16.h>

#define B_TOT 16384
#define C_CH  64
#define F_IN  128
#define H_HID 128
#define CG    4            // channels per block (2KB contiguous per row-chunk)
#define TROWS 32           // batch rows per tile (2 MFMA groups of 16)
#define NSUB  32           // tiles per block -> 1024 rows
#define ROWS  (NSUB * TROWS)

using f32x4  = __attribute__((ext_vector_type(4))) float;
using bf16x8 = __attribute__((ext_vector_type(8))) short;

__device__ inline unsigned pack2(float a, float b) {
    unsigned short lo = __builtin_bit_cast(unsigned short, __float2bfloat16(a));
    unsigned short hi = __builtin_bit_cast(unsigned short, __float2bfloat16(b));
    return (unsigned)lo | ((unsigned)hi << 16);
}

// async global->LDS, 16B/lane; LDS dest = wave-uniform base + lane*16 (HW rule)
__device__ inline void gld_lds16(const float* g, float* l) {
    __builtin_amdgcn_global_load_lds(
        (const __attribute__((address_space(1))) void*)g,
        (__attribute__((address_space(3))) void*)l, 16, 0, 0);
}

// Stage tile: 32 rows x 2KB (4 adjacent channels = contiguous span). Each
// instr reads a fully CONTIGUOUS 1KB (the r9 DRAM-page fix). Source-side XOR
// swizzle (lane ^ (row&7), within the 1KB) so ds_read_b128 is bank-balanced.
// LDS layout: float off = r*512 + h*256 + lane*4 holds global unit lane^sw.
__device__ inline void issue_tile(const float* __restrict__ X, size_t base0,
                                  int wave, int lane, float* buf) {
    #pragma unroll
    for (int q = 0; q < 4; ++q) {
        const int r = wave * 4 + q;                    // 8 waves x 4 rows = 32
        const float* rowp = X + base0 + (size_t)r * (C_CH * F_IN);
        const int sw = r & 7;
        #pragma unroll
        for (int h = 0; h < 2; ++h)
            gld_lds16(rowp + h * 256 + ((lane ^ sw) << 2),
                      buf + r * 512 + h * 256);
    }
}

// One 16-row MFMA group: W(regs) as A, X(LDS) as B => batch row lane-local;
// epilogue = in-lane relu-dot + 2 shuffles. b1 rides as MFMA C-init.
__device__ inline float compute_group(const float* __restrict__ xb, int g,
                                      const bf16x8 (&wf)[4][4],
                                      const f32x4 (&w2c)[4],
                                      const f32x4 (&b1c)[4],
                                      int l15, int lg, int ch)
{
    f32x4 acc[4];
    #pragma unroll
    for (int nf = 0; nf < 4; ++nf) acc[nf] = b1c[nf];

    const int sw = l15 & 7;                       // row = g*16 + l15; 16|g*16
    const int rb = (g * 16 + l15) * 512 + (ch >> 1) * 256;
    #pragma unroll
    for (int ks = 0; ks < 4; ++ks) {
        const int u = (ch & 1) * 32 + ks * 8 + lg * 2;
        float4 r0 = *reinterpret_cast<const float4*>(xb + rb + ((u ^ sw) << 2));
        float4 r1 = *reinterpret_cast<const float4*>(xb + rb + (((u + 1) ^ sw) << 2));
        uint4 px;
        px.x = pack2(r0.x, r0.y);
        px.y = pack2(r0.z, r0.w);
        px.z = pack2(r1.x, r1.y);
        px.w = pack2(r1.z, r1.w);
        bf16x8 xfrag = __builtin_bit_cast(bf16x8, px);
        #pragma unroll
        for (int nf = 0; nf < 4; ++nf)
            acc[nf] = __builtin_amdgcn_mfma_f32_16x16x32_bf16(
                wf[nf][ks], xfrag, acc[nf], 0, 0, 0);
    }

    float val = 0.f;
    #pragma unroll
    for (int nf = 0; nf < 4; ++nf)
        #pragma unroll
        for (int j = 0; j < 4; ++j)
            val += fmaxf(acc[nf][j], 0.f) * w2c[nf][j];
    val += __shfl_xor(val, 16, 64);   // sum the 4 lg-groups (h quarters)
    val += __shfl_xor(val, 32, 64);
    return val;
}

__global__ __launch_bounds__(512, 2)
void fused_mlp_kernel(const float* __restrict__ X,
                      const float* __restrict__ W1,
                      const float* __restrict__ b1,
                      const float* __restrict__ W2,
                      const float* __restrict__ b2,
                      float* __restrict__ out)
{
    __shared__ alignas(16) float Xs[2 * TROWS * 512];  // 2 bufs x 64KB = 128KB

    const int t    = threadIdx.x;
    const int lane = t & 63;
    const int wave = t >> 6;            // 8 waves: role = (ch, h-half)
    const int l15  = lane & 15;
    const int lg   = lane >> 4;
    const int ch   = wave & 3;
    const int hh   = wave >> 2;

    const int c0 = blockIdx.x * CG;
    const int c  = c0 + ch;
    const int m0 = blockIdx.y * ROWS;

    float* bu0 = Xs;
    float* bu1 = Xs + TROWS * 512;

    // prefill both buffers first: HBM latency hides under W-reg staging
    const size_t cbase = ((size_t)m0 * C_CH + c0) * F_IN;
    const size_t tstep = (size_t)TROWS * C_CH * F_IN;
    issue_tile(X, cbase, wave, lane, bu0);
    issue_tile(X, cbase + tstep, wave, lane, bu1);

    // ---- W1 fragments -> registers (64 VGPR): wave owns (channel, h-half) ----
    bf16x8 wf[4][4];
    {
        const float* wb = W1 + (size_t)c * F_IN * H_HID + hh * 64 + l15;
        #pragma unroll
        for (int nf = 0; nf < 4; ++nf)
            #pragma unroll
            for (int ks = 0; ks < 4; ++ks) {
                const int f0 = ks * 32 + lg * 8;
                float v[8];
                #pragma unroll
                for (int e = 0; e < 8; ++e)
                    v[e] = wb[(size_t)(f0 + e) * H_HID + nf * 16];
                uint4 p;
                p.x = pack2(v[0], v[1]);
                p.y = pack2(v[2], v[3]);
                p.z = pack2(v[4], v[5]);
                p.w = pack2(v[6], v[7]);
                wf[nf][ks] = __builtin_bit_cast(bf16x8, p);
            }
    }
    f32x4 w2c[4], b1c[4];
    #pragma unroll
    for (int nf = 0; nf < 4; ++nf) {
        const int ho = c * H_HID + hh * 64 + nf * 16 + lg * 4;
        w2c[nf] = *reinterpret_cast<const f32x4*>(W2 + ho);
        b1c[nf] = *reinterpret_cast<const f32x4*>(b1 + ho);
    }
    const float b2c = (hh == 0) ? b2[c] : 0.f;   // b2[c] added once per channel

    // ---- main loop: 31 barriers (was 63), counted vmcnt, 2-buf rotation ----
    // vm ops/round/wave: 8 gld_lds + 2 atomics, atomics AFTER next-tile loads
    // => tile sc retired <=> vmcnt <= 2 (in-order decrement). Never 0.
    #pragma unroll 1
    for (int sc = 0; sc < NSUB; ++sc) {
        asm volatile("s_waitcnt vmcnt(2)" ::: "memory");
        __builtin_amdgcn_s_barrier();      // all waves' slices in; prev reads done
        asm volatile("" ::: "memory");

        const float* xb = (sc & 1) ? bu1 : bu0;
        float*       nb = (sc & 1) ? bu0 : bu1;
        if (sc + 1 < NSUB)
            issue_tile(X, cbase + (size_t)(sc + 1) * tstep, wave, lane, nb);

        float v0 = compute_group(xb, 0, wf, w2c, b1c, l15, lg, ch);
        if (lane < 16) atomicAdd(&out[m0 + sc * TROWS + lane], v0 + b2c);
        float v1 = compute_group(xb, 1, wf, w2c, b1c, l15, lg, ch);
        if (lane < 16) atomicAdd(&out[m0 + sc * TROWS + 16 + lane], v1 + b2c);
    }
}

extern "C" void kernel_launch(void* const* d_in, const int* in_sizes, int n_in,
                              void* d_out, int out_size, void* d_ws, size_t ws_size,
                              hipStream_t stream) {
    const float* X  = (const float*)d_in[0];   // [B, C, F]
    const float* W1 = (const float*)d_in[1];   // [C, F, H]
    const float* b1 = (const float*)d_in[2];   // [C, H]
    const float* W2 = (const float*)d_in[3];   // [C, H]
    const float* b2 = (const float*)d_in[4];   // [C]
    float* out = (float*)d_out;                // [B]

    // atomics accumulate into out -> must zero it every call (d_out is poisoned)
    hipMemsetAsync(out, 0, (size_t)out_size * sizeof(float), stream);

    dim3 grid(C_CH / CG, B_TOT / ROWS);   // (16, 16) = 256 blocks = 1/CU
    fused_mlp_kernel<<<grid, dim3(512), 0, stream>>>(X, W1, b1, W2, b2, out);
}